// Round 26
// baseline (405.817 us; speedup 1.0000x reference)
//
#include <hip/hip_runtime.h>
#include <math.h>

#define DEV __device__ __forceinline__

typedef __bf16 bf16x8 __attribute__((ext_vector_type(8)));
typedef float f32x4 __attribute__((ext_vector_type(4)));
typedef unsigned short u16x8 __attribute__((ext_vector_type(8)));

typedef const __attribute__((address_space(1))) void gv_t;
typedef __attribute__((address_space(3))) void lv_t;

DEV unsigned short f2bf(float f){
  unsigned int u = __float_as_uint(f);
  u += 0x7fffu + ((u >> 16) & 1u);     // round-to-nearest-even
  return (unsigned short)(u >> 16);
}
DEV float bf2f(unsigned short u){ return __uint_as_float((unsigned)u << 16); }

DEV void gload16(const void* g, void* l){
  __builtin_amdgcn_global_load_lds((gv_t*)g, (lv_t*)l, 16, 0, 0);
}

// T1 chunked XCD swizzle (bijective when nwg%8==0, identity otherwise).
DEV void xcd_decode(int& bx, int& by, int& bz){
  const int gx = gridDim.x, gy = gridDim.y;
  const int nwg = gx * gy * gridDim.z;
  int lin = blockIdx.x + gx*(blockIdx.y + gy*blockIdx.z);
  if ((nwg & 7) == 0) lin = (lin & 7)*(nwg >> 3) + (lin >> 3);
  bx = lin % gx; const int t = lin / gx;
  by = t % gy;  bz = t / gy;
}

struct Proj3 {
  const unsigned short* A[3];
  const unsigned short* B[3];
  unsigned short*       C[3];
  const float*          bias[3];
};

// ---------------------------------------------------------------------------
// qkv256: three 4096x4096x512 projections.  Counted-vmcnt half-tile schedule
// with cross-sub A-frag register prefetch; BY-INNER xcd decode (R25: −5% on
// qkv via improved in-chunk L2 weight reuse).
// Proj 0/1 (Q,K): C[m][n] ldc 4096.  Proj 2 (V, swapped A=Wv^T B=x): vT.
// ---------------------------------------------------------------------------
__global__ __launch_bounds__(512, 2)
void qkv256(Proj3 pr)
{
  __shared__ unsigned short Ab[2][2][8192];   // [buf][half][128*64]
  __shared__ unsigned short Bb[2][2][8192];

  // by-inner bijective decode (nwg = 768 = 8 * 96)
  const int gx = gridDim.x, gy = gridDim.y;
  const int nwg = gx * gy * gridDim.z;
  int lin = blockIdx.x + gx*(blockIdx.y + gy*blockIdx.z);
  lin = (lin & 7)*(nwg >> 3) + (lin >> 3);
  const int byi = lin % gy;
  const int t2  = lin / gy;
  const int bxi = t2 % gx;
  const int bzi = t2 / gx;

  const int m0 = byi*256, n0 = bxi*256;
  const unsigned short* A = pr.A[bzi];
  const unsigned short* B = pr.B[bzi];
  unsigned short*       C = pr.C[bzi];
  const float*       bias = pr.bias[bzi];

  const int tid = threadIdx.x, lane = tid & 63, w = tid >> 6;
  const int wr = w >> 2, wc = w & 3;
  const int l15 = lane & 15, l4 = lane >> 4;

  const int r8  = tid >> 3;
  const int sc8 = ((tid & 7) ^ (r8 & 7)) * 8;

  auto stageA = [&](int buf, int half, int kt){
    #pragma unroll
    for (int j = 0; j < 2; j++){
      const int lr = j*64 + r8;
      gload16(A + (size_t)(m0 + half*128 + lr)*512 + kt + sc8,
              &Ab[buf][half][j*4096 + tid*8]);
    }
  };
  auto stageB = [&](int buf, int half, int kt){
    #pragma unroll
    for (int j = 0; j < 2; j++){
      const int lr = j*64 + r8;
      gload16(B + (size_t)(n0 + half*128 + lr)*512 + kt + sc8,
              &Bb[buf][half][j*4096 + tid*8]);
    }
  };
  auto readA = [&](bf16x8 (&dst)[2][2], int cur, int s){
    #pragma unroll
    for (int f = 0; f < 2; f++){
      const int lr = (s*2 + f)*16 + l15;
      #pragma unroll
      for (int kc = 0; kc < 2; kc++){
        const int cc = (kc*32 + l4*8) ^ ((lr & 7) * 8);
        dst[f][kc] = *(const bf16x8*)&Ab[cur][wr][lr*64 + cc];
      }
    }
  };

  f32x4 acc[8][4] = {};

  stageB(0,0,0); stageB(0,1,0);
  stageA(0,0,0); stageA(0,1,0);
  stageA(1,0,64); stageA(1,1,64);
  stageB(1,0,64); stageB(1,1,64);
  asm volatile("s_waitcnt vmcnt(8)" ::: "memory");
  __builtin_amdgcn_s_barrier();
  __builtin_amdgcn_sched_barrier(0);

  const int nt = 8;
  for (int Q = 0; Q < nt; Q++){
    const int cur = Q & 1;
    if (Q > 0){
      if (Q + 1 < nt) asm volatile("s_waitcnt vmcnt(4)" ::: "memory");
      else            asm volatile("s_waitcnt vmcnt(0)" ::: "memory");
      __builtin_amdgcn_s_barrier();
      __builtin_amdgcn_sched_barrier(0);
    }
    bf16x8 bfr[4][2];
    #pragma unroll
    for (int fc = 0; fc < 4; fc++){
      const int R = wc*64 + fc*16 + l15;
      const int hb = R >> 7, lr = R & 127;
      #pragma unroll
      for (int kc = 0; kc < 2; kc++){
        const int cc = (kc*32 + l4*8) ^ ((lr & 7) * 8);
        bfr[fc][kc] = *(const bf16x8*)&Bb[cur][hb][lr*64 + cc];
      }
    }
    bf16x8 ar0[2][2], ar1[2][2];
    readA(ar0, cur, 0);
    #pragma unroll
    for (int s = 0; s < 4; s++){
      if (s == 0) readA(ar1, cur, 1);
      if (s == 1) readA(ar0, cur, 2);
      if (s == 2) readA(ar1, cur, 3);
      if (s == 0 && Q >= 1 && Q + 1 < nt) stageA(cur ^ 1, 0, (Q+1)*64);
      if (s == 1 && Q >= 1 && Q + 1 < nt) stageA(cur ^ 1, 1, (Q+1)*64);
      if (s == 2 && Q + 2 < nt)           stageB(cur,     0, (Q+2)*64);
      if (s == 3 && Q + 2 < nt)           stageB(cur,     1, (Q+2)*64);

      if (s < 3) asm volatile("s_waitcnt lgkmcnt(4)" ::: "memory");
      else       asm volatile("s_waitcnt lgkmcnt(0)" ::: "memory");
      __builtin_amdgcn_sched_barrier(0);
      __builtin_amdgcn_s_setprio(1);
      #pragma unroll
      for (int f = 0; f < 2; f++)
        #pragma unroll
        for (int fc = 0; fc < 4; fc++)
          #pragma unroll
          for (int kc = 0; kc < 2; kc++)
            acc[s*2+f][fc] = __builtin_amdgcn_mfma_f32_16x16x32_bf16(
                (s & 1) ? ar1[f][kc] : ar0[f][kc], bfr[fc][kc],
                acc[s*2+f][fc], 0, 0, 0);
      __builtin_amdgcn_s_setprio(0);
      __builtin_amdgcn_s_barrier();
      __builtin_amdgcn_sched_barrier(0);
    }
  }

  if (bzi != 2){
    #pragma unroll
    for (int fr = 0; fr < 8; fr++){
      const int mb = m0 + wr*128 + fr*16 + l4*4;
      #pragma unroll
      for (int fc = 0; fc < 4; fc++){
        const int n = n0 + wc*64 + fc*16 + l15;
        const float bv = bias[n];
        #pragma unroll
        for (int r = 0; r < 4; r++)
          C[(size_t)(mb + r)*4096 + n] = f2bf(acc[fr][fc][r] + bv);
      }
    }
  } else {
    unsigned short* vt = C + ((size_t)((n0 >> 9)*8 + (m0 >> 9)))*262144;
    #pragma unroll
    for (int fr = 0; fr < 8; fr++){
      const int mb = m0 + wr*128 + fr*16 + l4*4;        // global m (bias idx)
      #pragma unroll
      for (int fc = 0; fc < 4; fc++){
        const int nl = (n0 & 256) + wc*64 + fc*16 + l15; // s within (b)
        #pragma unroll
        for (int r = 0; r < 4; r++){
          const int m = mb + r;
          const float bv = bias[m];
          vt[(size_t)((m0 & 256) + (m - m0))*512 + nl] = f2bf(acc[fr][fc][r] + bv);
        }
      }
    }
  }
}

// ---------------------------------------------------------------------------
// gemm256: counted-vmcnt half-tile schedule + cross-sub A-frag prefetch (R22).
// CMODE: 0=f32, 1=bf16. CSK: 0 none, 1 causal block-skip, 2 causal K-clamp.
// ---------------------------------------------------------------------------
template<int CMODE, int CSK>
__global__ __launch_bounds__(512, 2)
void gemm256(const unsigned short* __restrict__ A, const unsigned short* __restrict__ B,
             void* __restrict__ C, const float* __restrict__ bias,
             int M, int N, int K, int lda, int ldb, int ldc,
             size_t aOffH, size_t aOffB, size_t bOffH, size_t bOffB,
             size_t cOffH, size_t cOffB)
{
  __shared__ unsigned short Ab[2][2][8192];
  __shared__ unsigned short Bb[2][2][8192];

  int bxi, byi, bzi; xcd_decode(bxi, byi, bzi);
  const int m0 = byi*256, n0 = bxi*256;
  if (CSK == 1 && n0 > m0 + 255) return;

  const int z = bzi, bb = z >> 3, hh = z & 7;
  A += (size_t)bb*aOffB + (size_t)hh*aOffH;
  B += (size_t)bb*bOffB + (size_t)hh*bOffH;
  const size_t coff = (size_t)bb*cOffB + (size_t)hh*cOffH;

  const int tid = threadIdx.x, lane = tid & 63, w = tid >> 6;
  const int wr = w >> 2, wc = w & 3;
  const int l15 = lane & 15, l4 = lane >> 4;

  int Keff = K;
  if (CSK == 2) Keff = (m0 + 256 < K) ? (m0 + 256) : K;
  const int nt = Keff >> 6;

  const int r8  = tid >> 3;
  const int sc8 = ((tid & 7) ^ (r8 & 7)) * 8;

  auto stageA = [&](int buf, int half, int kt){
    #pragma unroll
    for (int j = 0; j < 2; j++){
      const int lr = j*64 + r8;
      gload16(A + (size_t)(m0 + half*128 + lr)*lda + kt + sc8,
              &Ab[buf][half][j*4096 + tid*8]);
    }
  };
  auto stageB = [&](int buf, int half, int kt){
    #pragma unroll
    for (int j = 0; j < 2; j++){
      const int lr = j*64 + r8;
      gload16(B + (size_t)(n0 + half*128 + lr)*ldb + kt + sc8,
              &Bb[buf][half][j*4096 + tid*8]);
    }
  };
  auto readA = [&](bf16x8 (&dst)[2][2], int cur, int s){
    #pragma unroll
    for (int f = 0; f < 2; f++){
      const int lr = (s*2 + f)*16 + l15;
      #pragma unroll
      for (int kc = 0; kc < 2; kc++){
        const int cc = (kc*32 + l4*8) ^ ((lr & 7) * 8);
        dst[f][kc] = *(const bf16x8*)&Ab[cur][wr][lr*64 + cc];
      }
    }
  };

  f32x4 acc[8][4] = {};

  stageB(0,0,0); stageB(0,1,0);
  stageA(0,0,0); stageA(0,1,0);
  if (nt > 1){
    stageA(1,0,64); stageA(1,1,64);
    stageB(1,0,64); stageB(1,1,64);
    asm volatile("s_waitcnt vmcnt(8)" ::: "memory");
  } else {
    asm volatile("s_waitcnt vmcnt(0)" ::: "memory");
  }
  __builtin_amdgcn_s_barrier();
  __builtin_amdgcn_sched_barrier(0);

  for (int Q = 0; Q < nt; Q++){
    const int cur = Q & 1;
    if (Q > 0){
      if (Q + 1 < nt) asm volatile("s_waitcnt vmcnt(4)" ::: "memory");
      else            asm volatile("s_waitcnt vmcnt(0)" ::: "memory");
      __builtin_amdgcn_s_barrier();
      __builtin_amdgcn_sched_barrier(0);
    }
    bf16x8 bfr[4][2];
    #pragma unroll
    for (int fc = 0; fc < 4; fc++){
      const int R = wc*64 + fc*16 + l15;
      const int hb = R >> 7, lr = R & 127;
      #pragma unroll
      for (int kc = 0; kc < 2; kc++){
        const int cc = (kc*32 + l4*8) ^ ((lr & 7) * 8);
        bfr[fc][kc] = *(const bf16x8*)&Bb[cur][hb][lr*64 + cc];
      }
    }
    bf16x8 ar0[2][2], ar1[2][2];
    readA(ar0, cur, 0);
    #pragma unroll
    for (int s = 0; s < 4; s++){
      if (s == 0) readA(ar1, cur, 1);
      if (s == 1) readA(ar0, cur, 2);
      if (s == 2) readA(ar1, cur, 3);
      if (s == 0 && Q >= 1 && Q + 1 < nt) stageA(cur ^ 1, 0, (Q+1)*64);
      if (s == 1 && Q >= 1 && Q + 1 < nt) stageA(cur ^ 1, 1, (Q+1)*64);
      if (s == 2 && Q + 2 < nt)           stageB(cur,     0, (Q+2)*64);
      if (s == 3 && Q + 2 < nt)           stageB(cur,     1, (Q+2)*64);

      if (s < 3) asm volatile("s_waitcnt lgkmcnt(4)" ::: "memory");
      else       asm volatile("s_waitcnt lgkmcnt(0)" ::: "memory");
      __builtin_amdgcn_sched_barrier(0);
      __builtin_amdgcn_s_setprio(1);
      #pragma unroll
      for (int f = 0; f < 2; f++)
        #pragma unroll
        for (int fc = 0; fc < 4; fc++)
          #pragma unroll
          for (int kc = 0; kc < 2; kc++)
            acc[s*2+f][fc] = __builtin_amdgcn_mfma_f32_16x16x32_bf16(
                (s & 1) ? ar1[f][kc] : ar0[f][kc], bfr[fc][kc],
                acc[s*2+f][fc], 0, 0, 0);
      __builtin_amdgcn_s_setprio(0);
      __builtin_amdgcn_s_barrier();
      __builtin_amdgcn_sched_barrier(0);
    }
  }

  #pragma unroll
  for (int fr = 0; fr < 8; fr++){
    const int mb = m0 + wr*128 + fr*16 + l4*4;
    #pragma unroll
    for (int fc = 0; fc < 4; fc++){
      const int n = n0 + wc*64 + fc*16 + l15;
      const float bv = bias ? bias[n] : 0.0f;
      #pragma unroll
      for (int r = 0; r < 4; r++){
        const float v = acc[fr][fc][r] + bv;
        if (CMODE == 0) ((float*)C)[coff + (size_t)(mb + r)*ldc + n] = v;
        else            ((unsigned short*)C)[coff + (size_t)(mb + r)*ldc + n] = f2bf(v);
      }
    }
  }
}

// ---------------------------------------------------------------------------
// gemm_bt: 128x128 tile, BK=64, 4 waves, 2-phase dbuf.  Per-z offsets for
// split-K partials.  CMODE: 0=f32, 1=bf16, 2=gelu.
// ---------------------------------------------------------------------------
template<int CMODE>
__global__ __launch_bounds__(256, 2)
void gemm_bt(const unsigned short* __restrict__ A, const unsigned short* __restrict__ B,
             void* __restrict__ C, const float* __restrict__ bias,
             int M, int N, int K, int lda, int ldb, int ldc,
             size_t aOffZ, size_t bOffZ, size_t cOffZ)
{
  __shared__ unsigned short Ab[2][8192];
  __shared__ unsigned short Bb[2][8192];

  int bxi, byi, bzi; xcd_decode(bxi, byi, bzi);
  const int m0 = byi*128, n0 = bxi*128;
  A += (size_t)bzi*aOffZ;
  B += (size_t)bzi*bOffZ;
  const size_t coff = (size_t)bzi*cOffZ;

  const int tid = threadIdx.x, lane = tid & 63, w = tid >> 6;
  const int wr = w >> 1, wc = w & 1;
  const int l15 = lane & 15, l4 = lane >> 4;
  const int nt = K >> 6;

  const int r8  = tid >> 3;
  const int sc8 = ((tid & 7) ^ (r8 & 7)) * 8;

  auto stage = [&](int buf, int kt){
    #pragma unroll
    for (int j = 0; j < 4; j++){
      gload16(A + (size_t)(m0 + j*32 + r8)*lda + kt + sc8, &Ab[buf][j*2048 + tid*8]);
      gload16(B + (size_t)(n0 + j*32 + r8)*ldb + kt + sc8, &Bb[buf][j*2048 + tid*8]);
    }
  };

  f32x4 acc[4][4] = {};

  stage(0, 0);
  __syncthreads();
  for (int t = 0; t < nt; t++){
    const int cur = t & 1;
    if (t + 1 < nt) stage(cur ^ 1, (t+1)*64);

    bf16x8 af[4][2], bfr[4][2];
    #pragma unroll
    for (int i = 0; i < 4; i++){
      const int Ra = wr*64 + i*16 + l15;
      const int Rb = wc*64 + i*16 + l15;
      #pragma unroll
      for (int kc = 0; kc < 2; kc++){
        const int ca = (kc*32 + l4*8) ^ ((Ra & 7) * 8);
        const int cb = (kc*32 + l4*8) ^ ((Rb & 7) * 8);
        af[i][kc]  = *(const bf16x8*)&Ab[cur][Ra*64 + ca];
        bfr[i][kc] = *(const bf16x8*)&Bb[cur][Rb*64 + cb];
      }
    }
    #pragma unroll
    for (int i = 0; i < 4; i++)
      #pragma unroll
      for (int jj = 0; jj < 4; jj++)
        #pragma unroll
        for (int kc = 0; kc < 2; kc++)
          acc[i][jj] = __builtin_amdgcn_mfma_f32_16x16x32_bf16(
              af[i][kc], bfr[jj][kc], acc[i][jj], 0, 0, 0);
    __syncthreads();
  }

  #pragma unroll
  for (int i = 0; i < 4; i++){
    const int mbase = m0 + wr*64 + i*16 + l4*4;
    #pragma unroll
    for (int jj = 0; jj < 4; jj++){
      const int n = n0 + wc*64 + jj*16 + l15;
      const float bv = bias ? bias[n] : 0.0f;
      #pragma unroll
      for (int r = 0; r < 4; r++){
        const int m = mbase + r;
        float v = acc[i][jj][r] + bv;
        if (CMODE == 0){
          ((float*)C)[coff + (size_t)m*ldc + n] = v;
        } else if (CMODE == 1){
          ((unsigned short*)C)[coff + (size_t)m*ldc + n] = f2bf(v);
        } else {
          v = 0.5f * v * (1.0f + erff(v * 0.70710678118654752f));   // exact GELU
          ((unsigned short*)C)[coff + (size_t)m*ldc + n] = f2bf(v);
        }
      }
    }
  }
}

// ---------------------------------------------------------------------------
// gelu_reduce2: out[i] = bf16(gelu(p0[i] + p1[i] + bias[i % 1024])).
// ---------------------------------------------------------------------------
__global__ __launch_bounds__(256)
void gelu_reduce2(const unsigned short* __restrict__ p, size_t pstride,
                  const float* __restrict__ bias, unsigned short* __restrict__ out)
{
  const size_t i = ((size_t)blockIdx.x*256 + threadIdx.x)*8;
  const int nb = (int)(i & 1023);
  u16x8 a = *(const u16x8*)(p + i);
  u16x8 b = *(const u16x8*)(p + pstride + i);
  u16x8 o;
  #pragma unroll
  for (int j = 0; j < 8; j++){
    float v = bf2f(a[j]) + bf2f(b[j]) + bias[nb + j];
    v = 0.5f * v * (1.0f + erff(v * 0.70710678118654752f));
    o[j] = f2bf(v);
  }
  *(u16x8*)(out + i) = o;
}

// ---------------------------------------------------------------------------
// Row softmax over bf16 scores [64][512][512], in-place.  One wave per row.
// ---------------------------------------------------------------------------
template<int CAUSAL>
__global__ __launch_bounds__(256)
void softmax_rows(unsigned short* __restrict__ scores)
{
  const int row  = blockIdx.x*4 + (threadIdx.x >> 6);
  const int lane = threadIdx.x & 63;
  const int q = row & 511;
  unsigned short* srow = scores + (size_t)row*512;
  u16x8 sv = {};
  if (!CAUSAL || lane*8 <= q) sv = *(const u16x8*)(srow + lane*8);
  float s[8]; float m = -1e30f;
  #pragma unroll
  for (int i = 0; i < 8; i++){
    const int col = lane*8 + i;
    float v = bf2f(sv[i]) * 0.044194173824159216f;   // 1/sqrt(512)
    if (CAUSAL && col > q) v = -1e30f;
    s[i] = v; m = fmaxf(m, v);
  }
  #pragma unroll
  for (int o = 32; o; o >>= 1) m = fmaxf(m, __shfl_xor(m, o));
  float p[8], sum = 0.f;
  #pragma unroll
  for (int i = 0; i < 8; i++){
    float e = __expf(s[i] - m);
    if (CAUSAL && (lane*8 + i) > q) e = 0.f;
    p[i] = e; sum += e;
  }
  #pragma unroll
  for (int o = 32; o; o >>= 1) sum += __shfl_xor(sum, o);
  const float inv = 1.0f / sum;
  u16x8 pv;
  #pragma unroll
  for (int i = 0; i < 8; i++) pv[i] = f2bf(p[i] * inv);
  *(u16x8*)(srow + lane*8) = pv;
}

// ---------------------------------------------------------------------------
// y = LayerNorm(x + sum_{p<ND} partial_p + bias) * g + b.
// XF32: x is f32 (else bf16).  OUTF32: write f32 (else bf16).
// ---------------------------------------------------------------------------
template<int XF32, int OUTF32, int ND>
__global__ __launch_bounds__(256)
void ln_rows(const void* __restrict__ x, const unsigned short* __restrict__ dbase,
             size_t dstride, const float* __restrict__ bias,
             const float* __restrict__ g, const float* __restrict__ bta,
             void* __restrict__ out)
{
  const int row = blockIdx.x*4 + (threadIdx.x >> 6);
  const int lane = threadIdx.x & 63;
  float v[8];
  if (XF32){
    const float* xr = (const float*)x + (size_t)row*512 + lane*8;
    #pragma unroll
    for (int i = 0; i < 8; i++) v[i] = xr[i];
  } else {
    u16x8 xv = *(const u16x8*)((const unsigned short*)x + (size_t)row*512 + lane*8);
    #pragma unroll
    for (int i = 0; i < 8; i++) v[i] = bf2f(xv[i]);
  }
  #pragma unroll
  for (int i = 0; i < 8; i++) v[i] += bias ? bias[lane*8 + i] : 0.0f;
  #pragma unroll
  for (int p = 0; p < ND; p++){
    u16x8 dv = *(const u16x8*)(dbase + p*dstride + (size_t)row*512 + lane*8);
    #pragma unroll
    for (int i = 0; i < 8; i++) v[i] += bf2f(dv[i]);
  }
  float sum = 0.f;
  #pragma unroll
  for (int i = 0; i < 8; i++) sum += v[i];
  #pragma unroll
  for (int o = 32; o; o >>= 1) sum += __shfl_xor(sum, o);
  const float mean = sum * (1.0f/512.0f);
  float s2 = 0.f;
  #pragma unroll
  for (int i = 0; i < 8; i++){ const float t = v[i] - mean; s2 += t*t; }
  #pragma unroll
  for (int o = 32; o; o >>= 1) s2 += __shfl_xor(s2, o);
  const float inv = rsqrtf(s2 * (1.0f/512.0f) + 1e-3f);
  if (OUTF32){
    float* po = (float*)out + (size_t)row*512 + lane*8;
    #pragma unroll
    for (int i = 0; i < 8; i++){
      const int c = lane*8 + i;
      po[i] = (v[i] - mean)*inv*g[c] + bta[c];
    }
  } else {
    u16x8 ov;
    #pragma unroll
    for (int i = 0; i < 8; i++){
      const int c = lane*8 + i;
      ov[i] = f2bf((v[i] - mean)*inv*g[c] + bta[c]);
    }
    *(u16x8*)((unsigned short*)out + (size_t)row*512 + lane*8) = ov;
  }
}

struct Cast2 { const float* s[2]; unsigned short* d[2]; };

__global__ __launch_bounds__(256)
void cast_bf16_k2(Cast2 a, int n)
{
  const int z = blockIdx.y;
  const int i = (blockIdx.x*256 + threadIdx.x)*4;
  if (i < n){
    const float4 v = *(const float4*)(a.s[z] + i);
    uint2 o;
    o.x = (unsigned)f2bf(v.x) | ((unsigned)f2bf(v.y) << 16);
    o.y = (unsigned)f2bf(v.z) | ((unsigned)f2bf(v.w) << 16);
    *(uint2*)(a.d[z] + i) = o;
  }
}

// ---------------------------------------------------------------------------
// transpose_cast_all: 10 weight tensors, one dispatch.
// ---------------------------------------------------------------------------
struct TCA {
  const float* s[10]; unsigned short* d[10];
  int Cc[10]; int Rr[10]; int cw[10];
  int start[11];
};

__global__ __launch_bounds__(256)
void transpose_cast_all(TCA a)
{
  __shared__ float tile[32][33];
  const int bid = blockIdx.x;
  int t = 0;
  #pragma unroll
  for (int k = 0; k < 9; k++) if (bid >= a.start[k+1]) t = k+1;
  const float* src = a.s[t];
  unsigned short* dst = a.d[t];
  const int C = a.Cc[t], R = a.Rr[t];
  const int local = bid - a.start[t];
  const int bx = (local % a.cw[t])*32, by = (local / a.cw[t])*32;
  const int tx = threadIdx.x & 31, ty = threadIdx.x >> 5;
  #pragma unroll
  for (int i = 0; i < 32; i += 8) tile[ty + i][tx] = src[(size_t)(by + ty + i)*C + bx + tx];
  __syncthreads();
  #pragma unroll
  for (int i = 0; i < 32; i += 8) dst[(size_t)(bx + ty + i)*R + by + tx] = f2bf(tile[tx][ty + i]);
}

// ---------------------------------------------------------------------------
extern "C" void kernel_launch(void* const* d_in, const int* in_sizes, int n_in,
                              void* d_out, int out_size, void* d_ws, size_t ws_size,
                              hipStream_t stream)
{
  (void)in_sizes; (void)n_in; (void)out_size; (void)ws_size;

  const float* in_seq  = (const float*)d_in[0];
  const float* out_seq = (const float*)d_in[1];
  const float* sa_wq = (const float*)d_in[2];  const float* sa_bq = (const float*)d_in[3];
  const float* sa_wk = (const float*)d_in[4];  const float* sa_bk = (const float*)d_in[5];
  const float* sa_wv = (const float*)d_in[6];  const float* sa_bv = (const float*)d_in[7];
  const float* sa_wo = (const float*)d_in[8];  const float* sa_bo = (const float*)d_in[9];
  const float* sa_lng = (const float*)d_in[10]; const float* sa_lnb = (const float*)d_in[11];
  const float* ca_wq = (const float*)d_in[12]; const float* ca_bq = (const float*)d_in[13];
  const float* ca_wk = (const float*)d_in[14]; const float* ca_bk = (const float*)d_in[15];
  const float* ca_wv = (const float*)d_in[16]; const float* ca_bv = (const float*)d_in[17];
  const float* ca_wo = (const float*)d_in[18]; const float* ca_bo = (const float*)d_in[19];
  const float* ca_lng = (const float*)d_in[20]; const float* ca_lnb = (const float*)d_in[21];
  const float* ff_w1 = (const float*)d_in[22]; const float* ff_b1 = (const float*)d_in[23];
  const float* ff_w2 = (const float*)d_in[24]; const float* ff_b2 = (const float*)d_in[25];
  const float* ff_lng = (const float*)d_in[26]; const float* ff_lnb = (const float*)d_in[27];

  char* ws = (char*)d_ws;
  size_t off = 0;
  auto alloc = [&](size_t bytes){ char* p = ws + off; off += (bytes + 255) & ~(size_t)255; return p; };

  unsigned short* wT[8];
  for (int i = 0; i < 8; i++) wT[i] = (unsigned short*)alloc(4096ULL*512*2);
  unsigned short* w1T  = (unsigned short*)alloc(1024ULL*512*2);
  unsigned short* w2T  = (unsigned short*)alloc(512ULL*1024*2);
  unsigned short* xbf  = (unsigned short*)alloc(4096ULL*512*2);   // running residual (bf16)
  unsigned short* inbf = (unsigned short*)alloc(4096ULL*512*2);
  unsigned short* qb   = (unsigned short*)alloc(4096ULL*4096*2);  // also FFN hidden
  unsigned short* kb   = (unsigned short*)alloc(4096ULL*4096*2);  // also attn-out
  unsigned short* vT   = (unsigned short*)alloc(64ULL*512*512*2);
  unsigned short* scb  = (unsigned short*)alloc(64ULL*512*512*2); // scores/probs/partials

  unsigned short* part = scb;
  const size_t PART_STRIDE = 2097152;   // ushorts per [4096][512] slice
  const size_t FF1_STRIDE = 4194304;    // ushorts per [4096][1024] slice

  // ---- prologue ----
  Cast2 c2{{out_seq, in_seq}, {xbf, inbf}};
  cast_bf16_k2<<<dim3(2048,2), 256, 0, stream>>>(c2, 4096*512);

  TCA ta;
  const float* srcs[10] = {sa_wq, sa_wk, sa_wv, ca_wq, ca_wk, ca_wv, sa_wo, ca_wo, ff_w1, ff_w2};
  unsigned short* dsts[10] = {wT[0], wT[1], wT[2], wT[4], wT[5], wT[6], wT[3], wT[7], w1T, w2T};
  const int Rs[10] = {512,512,512,512,512,512, 4096,4096, 512, 1024};
  const int Cs[10] = {4096,4096,4096,4096,4096,4096, 512,512, 1024, 512};
  int acc_ = 0;
  for (int t = 0; t < 10; t++){
    ta.s[t] = srcs[t]; ta.d[t] = dsts[t];
    ta.Rr[t] = Rs[t]; ta.Cc[t] = Cs[t]; ta.cw[t] = Cs[t]/32;
    ta.start[t] = acc_;
    acc_ += (Cs[t]/32)*(Rs[t]/32);
  }
  ta.start[10] = acc_;
  transpose_cast_all<<<acc_, 256, 0, stream>>>(ta);

  #define G256(MODE, CSK, Apt, Bpt, Cpt, BIAS, M, N, K, LDA, LDB, LDC, Z, aH, aB, bH, bB, cH, cB) \
    gemm256<MODE, CSK><<<dim3((N)/256,(M)/256,(Z)), 512, 0, stream>>>( \
      (const unsigned short*)(Apt), (const unsigned short*)(Bpt), (void*)(Cpt), BIAS, \
      M, N, K, LDA, LDB, LDC, aH, aB, bH, bB, cH, cB)

  // ---- self-attention (causal) ----
  Proj3 saP{{xbf, xbf, wT[2]}, {wT[0], wT[1], xbf}, {qb, kb, vT}, {sa_bq, sa_bk, sa_bv}};
  qkv256<<<dim3(16,16,3), 512, 0, stream>>>(saP);
  G256(1, 1, qb, kb, scb, nullptr, 512, 512, 512, 4096, 4096, 512, 64,
       512, 2097152, 512, 2097152, 262144, 2097152);
  softmax_rows<1><<<8192, 256, 0, stream>>>(scb);
  G256(1, 2, scb, vT, kb, nullptr, 512, 512, 512, 512, 512, 4096, 64,
       262144, 2097152, 262144, 2097152, 512, 2097152);
  G256(1, 0, kb, wT[3], part, nullptr, 4096, 512, 512, 4096, 4096, 512, 8,
       512, 0, 512, 0, PART_STRIDE, 0);
  ln_rows<1, 0, 8><<<1024, 256, 0, stream>>>(out_seq, part, PART_STRIDE,
                                             sa_bo, sa_lng, sa_lnb, xbf);

  // ---- cross-attention ----
  Proj3 caP{{xbf, inbf, wT[6]}, {wT[4], wT[5], inbf}, {qb, kb, vT}, {ca_bq, ca_bk, ca_bv}};
  qkv256<<<dim3(16,16,3), 512, 0, stream>>>(caP);
  G256(1, 0, qb, kb, scb, nullptr, 512, 512, 512, 4096, 4096, 512, 64,
       512, 2097152, 512, 2097152, 262144, 2097152);
  softmax_rows<0><<<8192, 256, 0, stream>>>(scb);
  G256(1, 0, scb, vT, kb, nullptr, 512, 512, 512, 512, 512, 4096, 64,
       262144, 2097152, 262144, 2097152, 512, 2097152);
  G256(1, 0, kb, wT[7], part, nullptr, 4096, 512, 512, 4096, 4096, 512, 8,
       512, 0, 512, 0, PART_STRIDE, 0);
  ln_rows<0, 0, 8><<<1024, 256, 0, stream>>>(xbf, part, PART_STRIDE,
                                             ca_bo, ca_lng, ca_lnb, xbf);

  // ---- FFN ----
  gemm_bt<1><<<dim3(8,32,2), 256, 0, stream>>>(
      xbf, w1T, (void*)part, nullptr, 4096, 1024, 256, 512, 512, 1024,
      256, 256, FF1_STRIDE);
  gelu_reduce2<<<2048, 256, 0, stream>>>(part, FF1_STRIDE, ff_b1, qb);
  G256(1, 0, qb, w2T, part, nullptr, 4096, 512, 128, 1024, 1024, 512, 8,
       128, 0, 128, 0, PART_STRIDE, 0);
  ln_rows<0, 1, 8><<<1024, 256, 0, stream>>>(xbf, part, PART_STRIDE,
                                             ff_b2, ff_lng, ff_lnb, (float*)d_out);

  #undef G256
}

// Round 27
// 401.191 us; speedup vs baseline: 1.0115x; 1.0115x over previous
//
#include <hip/hip_runtime.h>
#include <math.h>

#define DEV __device__ __forceinline__

typedef __bf16 bf16x8 __attribute__((ext_vector_type(8)));
typedef float f32x4 __attribute__((ext_vector_type(4)));
typedef unsigned short u16x8 __attribute__((ext_vector_type(8)));

typedef const __attribute__((address_space(1))) void gv_t;
typedef __attribute__((address_space(3))) void lv_t;

DEV unsigned short f2bf(float f){
  unsigned int u = __float_as_uint(f);
  u += 0x7fffu + ((u >> 16) & 1u);     // round-to-nearest-even
  return (unsigned short)(u >> 16);
}
DEV float bf2f(unsigned short u){ return __uint_as_float((unsigned)u << 16); }

DEV void gload16(const void* g, void* l){
  __builtin_amdgcn_global_load_lds((gv_t*)g, (lv_t*)l, 16, 0, 0);
}

// T1 chunked XCD swizzle (bijective when nwg%8==0, identity otherwise).
DEV void xcd_decode(int& bx, int& by, int& bz){
  const int gx = gridDim.x, gy = gridDim.y;
  const int nwg = gx * gy * gridDim.z;
  int lin = blockIdx.x + gx*(blockIdx.y + gy*blockIdx.z);
  if ((nwg & 7) == 0) lin = (lin & 7)*(nwg >> 3) + (lin >> 3);
  bx = lin % gx; const int t = lin / gx;
  by = t % gy;  bz = t / gy;
}

struct Proj3 {
  const unsigned short* A[3];
  const unsigned short* B[3];
  unsigned short*       C[3];
  const float*          bias[3];
};

// ---------------------------------------------------------------------------
// qkv256: three 4096x4096x512 projections.  Counted-vmcnt half-tile schedule
// with cross-sub A-frag register prefetch; BY-INNER xcd decode (R25: −5% on
// qkv via improved in-chunk L2 weight reuse).
// Proj 0/1 (Q,K): C[m][n] ldc 4096.  Proj 2 (V, swapped A=Wv^T B=x): vT.
// ---------------------------------------------------------------------------
__global__ __launch_bounds__(512, 2)
void qkv256(Proj3 pr)
{
  __shared__ unsigned short Ab[2][2][8192];   // [buf][half][128*64]
  __shared__ unsigned short Bb[2][2][8192];

  // by-inner bijective decode (nwg = 768 = 8 * 96)
  const int gx = gridDim.x, gy = gridDim.y;
  const int nwg = gx * gy * gridDim.z;
  int lin = blockIdx.x + gx*(blockIdx.y + gy*blockIdx.z);
  lin = (lin & 7)*(nwg >> 3) + (lin >> 3);
  const int byi = lin % gy;
  const int t2  = lin / gy;
  const int bxi = t2 % gx;
  const int bzi = t2 / gx;

  const int m0 = byi*256, n0 = bxi*256;
  const unsigned short* A = pr.A[bzi];
  const unsigned short* B = pr.B[bzi];
  unsigned short*       C = pr.C[bzi];
  const float*       bias = pr.bias[bzi];

  const int tid = threadIdx.x, lane = tid & 63, w = tid >> 6;
  const int wr = w >> 2, wc = w & 3;
  const int l15 = lane & 15, l4 = lane >> 4;

  const int r8  = tid >> 3;
  const int sc8 = ((tid & 7) ^ (r8 & 7)) * 8;

  auto stageA = [&](int buf, int half, int kt){
    #pragma unroll
    for (int j = 0; j < 2; j++){
      const int lr = j*64 + r8;
      gload16(A + (size_t)(m0 + half*128 + lr)*512 + kt + sc8,
              &Ab[buf][half][j*4096 + tid*8]);
    }
  };
  auto stageB = [&](int buf, int half, int kt){
    #pragma unroll
    for (int j = 0; j < 2; j++){
      const int lr = j*64 + r8;
      gload16(B + (size_t)(n0 + half*128 + lr)*512 + kt + sc8,
              &Bb[buf][half][j*4096 + tid*8]);
    }
  };
  auto readA = [&](bf16x8 (&dst)[2][2], int cur, int s){
    #pragma unroll
    for (int f = 0; f < 2; f++){
      const int lr = (s*2 + f)*16 + l15;
      #pragma unroll
      for (int kc = 0; kc < 2; kc++){
        const int cc = (kc*32 + l4*8) ^ ((lr & 7) * 8);
        dst[f][kc] = *(const bf16x8*)&Ab[cur][wr][lr*64 + cc];
      }
    }
  };

  f32x4 acc[8][4] = {};

  stageB(0,0,0); stageB(0,1,0);
  stageA(0,0,0); stageA(0,1,0);
  stageA(1,0,64); stageA(1,1,64);
  stageB(1,0,64); stageB(1,1,64);
  asm volatile("s_waitcnt vmcnt(8)" ::: "memory");
  __builtin_amdgcn_s_barrier();
  __builtin_amdgcn_sched_barrier(0);

  const int nt = 8;
  for (int Q = 0; Q < nt; Q++){
    const int cur = Q & 1;
    if (Q > 0){
      if (Q + 1 < nt) asm volatile("s_waitcnt vmcnt(4)" ::: "memory");
      else            asm volatile("s_waitcnt vmcnt(0)" ::: "memory");
      __builtin_amdgcn_s_barrier();
      __builtin_amdgcn_sched_barrier(0);
    }
    bf16x8 bfr[4][2];
    #pragma unroll
    for (int fc = 0; fc < 4; fc++){
      const int R = wc*64 + fc*16 + l15;
      const int hb = R >> 7, lr = R & 127;
      #pragma unroll
      for (int kc = 0; kc < 2; kc++){
        const int cc = (kc*32 + l4*8) ^ ((lr & 7) * 8);
        bfr[fc][kc] = *(const bf16x8*)&Bb[cur][hb][lr*64 + cc];
      }
    }
    bf16x8 ar0[2][2], ar1[2][2];
    readA(ar0, cur, 0);
    #pragma unroll
    for (int s = 0; s < 4; s++){
      if (s == 0) readA(ar1, cur, 1);
      if (s == 1) readA(ar0, cur, 2);
      if (s == 2) readA(ar1, cur, 3);
      if (s == 0 && Q >= 1 && Q + 1 < nt) stageA(cur ^ 1, 0, (Q+1)*64);
      if (s == 1 && Q >= 1 && Q + 1 < nt) stageA(cur ^ 1, 1, (Q+1)*64);
      if (s == 2 && Q + 2 < nt)           stageB(cur,     0, (Q+2)*64);
      if (s == 3 && Q + 2 < nt)           stageB(cur,     1, (Q+2)*64);

      if (s < 3) asm volatile("s_waitcnt lgkmcnt(4)" ::: "memory");
      else       asm volatile("s_waitcnt lgkmcnt(0)" ::: "memory");
      __builtin_amdgcn_sched_barrier(0);
      __builtin_amdgcn_s_setprio(1);
      #pragma unroll
      for (int f = 0; f < 2; f++)
        #pragma unroll
        for (int fc = 0; fc < 4; fc++)
          #pragma unroll
          for (int kc = 0; kc < 2; kc++)
            acc[s*2+f][fc] = __builtin_amdgcn_mfma_f32_16x16x32_bf16(
                (s & 1) ? ar1[f][kc] : ar0[f][kc], bfr[fc][kc],
                acc[s*2+f][fc], 0, 0, 0);
      __builtin_amdgcn_s_setprio(0);
      __builtin_amdgcn_s_barrier();
      __builtin_amdgcn_sched_barrier(0);
    }
  }

  if (bzi != 2){
    #pragma unroll
    for (int fr = 0; fr < 8; fr++){
      const int mb = m0 + wr*128 + fr*16 + l4*4;
      #pragma unroll
      for (int fc = 0; fc < 4; fc++){
        const int n = n0 + wc*64 + fc*16 + l15;
        const float bv = bias[n];
        #pragma unroll
        for (int r = 0; r < 4; r++)
          C[(size_t)(mb + r)*4096 + n] = f2bf(acc[fr][fc][r] + bv);
      }
    }
  } else {
    unsigned short* vt = C + ((size_t)((n0 >> 9)*8 + (m0 >> 9)))*262144;
    #pragma unroll
    for (int fr = 0; fr < 8; fr++){
      const int mb = m0 + wr*128 + fr*16 + l4*4;        // global m (bias idx)
      #pragma unroll
      for (int fc = 0; fc < 4; fc++){
        const int nl = (n0 & 256) + wc*64 + fc*16 + l15; // s within (b)
        #pragma unroll
        for (int r = 0; r < 4; r++){
          const int m = mb + r;
          const float bv = bias[m];
          vt[(size_t)((m0 & 256) + (m - m0))*512 + nl] = f2bf(acc[fr][fc][r] + bv);
        }
      }
    }
  }
}

// ---------------------------------------------------------------------------
// gemm256: counted-vmcnt half-tile schedule + cross-sub A-frag prefetch (R22).
// CMODE: 0=f32, 1=bf16. CSK: 0 none, 1 causal block-skip, 2 causal K-clamp.
// ---------------------------------------------------------------------------
template<int CMODE, int CSK>
__global__ __launch_bounds__(512, 2)
void gemm256(const unsigned short* __restrict__ A, const unsigned short* __restrict__ B,
             void* __restrict__ C, const float* __restrict__ bias,
             int M, int N, int K, int lda, int ldb, int ldc,
             size_t aOffH, size_t aOffB, size_t bOffH, size_t bOffB,
             size_t cOffH, size_t cOffB)
{
  __shared__ unsigned short Ab[2][2][8192];
  __shared__ unsigned short Bb[2][2][8192];

  int bxi, byi, bzi; xcd_decode(bxi, byi, bzi);
  const int m0 = byi*256, n0 = bxi*256;
  if (CSK == 1 && n0 > m0 + 255) return;

  const int z = bzi, bb = z >> 3, hh = z & 7;
  A += (size_t)bb*aOffB + (size_t)hh*aOffH;
  B += (size_t)bb*bOffB + (size_t)hh*bOffH;
  const size_t coff = (size_t)bb*cOffB + (size_t)hh*cOffH;

  const int tid = threadIdx.x, lane = tid & 63, w = tid >> 6;
  const int wr = w >> 2, wc = w & 3;
  const int l15 = lane & 15, l4 = lane >> 4;

  int Keff = K;
  if (CSK == 2) Keff = (m0 + 256 < K) ? (m0 + 256) : K;
  const int nt = Keff >> 6;

  const int r8  = tid >> 3;
  const int sc8 = ((tid & 7) ^ (r8 & 7)) * 8;

  auto stageA = [&](int buf, int half, int kt){
    #pragma unroll
    for (int j = 0; j < 2; j++){
      const int lr = j*64 + r8;
      gload16(A + (size_t)(m0 + half*128 + lr)*lda + kt + sc8,
              &Ab[buf][half][j*4096 + tid*8]);
    }
  };
  auto stageB = [&](int buf, int half, int kt){
    #pragma unroll
    for (int j = 0; j < 2; j++){
      const int lr = j*64 + r8;
      gload16(B + (size_t)(n0 + half*128 + lr)*ldb + kt + sc8,
              &Bb[buf][half][j*4096 + tid*8]);
    }
  };
  auto readA = [&](bf16x8 (&dst)[2][2], int cur, int s){
    #pragma unroll
    for (int f = 0; f < 2; f++){
      const int lr = (s*2 + f)*16 + l15;
      #pragma unroll
      for (int kc = 0; kc < 2; kc++){
        const int cc = (kc*32 + l4*8) ^ ((lr & 7) * 8);
        dst[f][kc] = *(const bf16x8*)&Ab[cur][wr][lr*64 + cc];
      }
    }
  };

  f32x4 acc[8][4] = {};

  stageB(0,0,0); stageB(0,1,0);
  stageA(0,0,0); stageA(0,1,0);
  if (nt > 1){
    stageA(1,0,64); stageA(1,1,64);
    stageB(1,0,64); stageB(1,1,64);
    asm volatile("s_waitcnt vmcnt(8)" ::: "memory");
  } else {
    asm volatile("s_waitcnt vmcnt(0)" ::: "memory");
  }
  __builtin_amdgcn_s_barrier();
  __builtin_amdgcn_sched_barrier(0);

  for (int Q = 0; Q < nt; Q++){
    const int cur = Q & 1;
    if (Q > 0){
      if (Q + 1 < nt) asm volatile("s_waitcnt vmcnt(4)" ::: "memory");
      else            asm volatile("s_waitcnt vmcnt(0)" ::: "memory");
      __builtin_amdgcn_s_barrier();
      __builtin_amdgcn_sched_barrier(0);
    }
    bf16x8 bfr[4][2];
    #pragma unroll
    for (int fc = 0; fc < 4; fc++){
      const int R = wc*64 + fc*16 + l15;
      const int hb = R >> 7, lr = R & 127;
      #pragma unroll
      for (int kc = 0; kc < 2; kc++){
        const int cc = (kc*32 + l4*8) ^ ((lr & 7) * 8);
        bfr[fc][kc] = *(const bf16x8*)&Bb[cur][hb][lr*64 + cc];
      }
    }
    bf16x8 ar0[2][2], ar1[2][2];
    readA(ar0, cur, 0);
    #pragma unroll
    for (int s = 0; s < 4; s++){
      if (s == 0) readA(ar1, cur, 1);
      if (s == 1) readA(ar0, cur, 2);
      if (s == 2) readA(ar1, cur, 3);
      if (s == 0 && Q >= 1 && Q + 1 < nt) stageA(cur ^ 1, 0, (Q+1)*64);
      if (s == 1 && Q >= 1 && Q + 1 < nt) stageA(cur ^ 1, 1, (Q+1)*64);
      if (s == 2 && Q + 2 < nt)           stageB(cur,     0, (Q+2)*64);
      if (s == 3 && Q + 2 < nt)           stageB(cur,     1, (Q+2)*64);

      if (s < 3) asm volatile("s_waitcnt lgkmcnt(4)" ::: "memory");
      else       asm volatile("s_waitcnt lgkmcnt(0)" ::: "memory");
      __builtin_amdgcn_sched_barrier(0);
      __builtin_amdgcn_s_setprio(1);
      #pragma unroll
      for (int f = 0; f < 2; f++)
        #pragma unroll
        for (int fc = 0; fc < 4; fc++)
          #pragma unroll
          for (int kc = 0; kc < 2; kc++)
            acc[s*2+f][fc] = __builtin_amdgcn_mfma_f32_16x16x32_bf16(
                (s & 1) ? ar1[f][kc] : ar0[f][kc], bfr[fc][kc],
                acc[s*2+f][fc], 0, 0, 0);
      __builtin_amdgcn_s_setprio(0);
      __builtin_amdgcn_s_barrier();
      __builtin_amdgcn_sched_barrier(0);
    }
  }

  #pragma unroll
  for (int fr = 0; fr < 8; fr++){
    const int mb = m0 + wr*128 + fr*16 + l4*4;
    #pragma unroll
    for (int fc = 0; fc < 4; fc++){
      const int n = n0 + wc*64 + fc*16 + l15;
      const float bv = bias ? bias[n] : 0.0f;
      #pragma unroll
      for (int r = 0; r < 4; r++){
        const float v = acc[fr][fc][r] + bv;
        if (CMODE == 0) ((float*)C)[coff + (size_t)(mb + r)*ldc + n] = v;
        else            ((unsigned short*)C)[coff + (size_t)(mb + r)*ldc + n] = f2bf(v);
      }
    }
  }
}

// ---------------------------------------------------------------------------
// gemm_bt: 128x128 tile, BK=64, 4 waves, 2-phase dbuf.  Per-z offsets for
// split-K partials.  CMODE: 0=f32, 1=bf16, 2=gelu.
// ---------------------------------------------------------------------------
template<int CMODE>
__global__ __launch_bounds__(256, 2)
void gemm_bt(const unsigned short* __restrict__ A, const unsigned short* __restrict__ B,
             void* __restrict__ C, const float* __restrict__ bias,
             int M, int N, int K, int lda, int ldb, int ldc,
             size_t aOffZ, size_t bOffZ, size_t cOffZ)
{
  __shared__ unsigned short Ab[2][8192];
  __shared__ unsigned short Bb[2][8192];

  int bxi, byi, bzi; xcd_decode(bxi, byi, bzi);
  const int m0 = byi*128, n0 = bxi*128;
  A += (size_t)bzi*aOffZ;
  B += (size_t)bzi*bOffZ;
  const size_t coff = (size_t)bzi*cOffZ;

  const int tid = threadIdx.x, lane = tid & 63, w = tid >> 6;
  const int wr = w >> 1, wc = w & 1;
  const int l15 = lane & 15, l4 = lane >> 4;
  const int nt = K >> 6;

  const int r8  = tid >> 3;
  const int sc8 = ((tid & 7) ^ (r8 & 7)) * 8;

  auto stage = [&](int buf, int kt){
    #pragma unroll
    for (int j = 0; j < 4; j++){
      gload16(A + (size_t)(m0 + j*32 + r8)*lda + kt + sc8, &Ab[buf][j*2048 + tid*8]);
      gload16(B + (size_t)(n0 + j*32 + r8)*ldb + kt + sc8, &Bb[buf][j*2048 + tid*8]);
    }
  };

  f32x4 acc[4][4] = {};

  stage(0, 0);
  __syncthreads();
  for (int t = 0; t < nt; t++){
    const int cur = t & 1;
    if (t + 1 < nt) stage(cur ^ 1, (t+1)*64);

    bf16x8 af[4][2], bfr[4][2];
    #pragma unroll
    for (int i = 0; i < 4; i++){
      const int Ra = wr*64 + i*16 + l15;
      const int Rb = wc*64 + i*16 + l15;
      #pragma unroll
      for (int kc = 0; kc < 2; kc++){
        const int ca = (kc*32 + l4*8) ^ ((Ra & 7) * 8);
        const int cb = (kc*32 + l4*8) ^ ((Rb & 7) * 8);
        af[i][kc]  = *(const bf16x8*)&Ab[cur][Ra*64 + ca];
        bfr[i][kc] = *(const bf16x8*)&Bb[cur][Rb*64 + cb];
      }
    }
    #pragma unroll
    for (int i = 0; i < 4; i++)
      #pragma unroll
      for (int jj = 0; jj < 4; jj++)
        #pragma unroll
        for (int kc = 0; kc < 2; kc++)
          acc[i][jj] = __builtin_amdgcn_mfma_f32_16x16x32_bf16(
              af[i][kc], bfr[jj][kc], acc[i][jj], 0, 0, 0);
    __syncthreads();
  }

  #pragma unroll
  for (int i = 0; i < 4; i++){
    const int mbase = m0 + wr*64 + i*16 + l4*4;
    #pragma unroll
    for (int jj = 0; jj < 4; jj++){
      const int n = n0 + wc*64 + jj*16 + l15;
      const float bv = bias ? bias[n] : 0.0f;
      #pragma unroll
      for (int r = 0; r < 4; r++){
        const int m = mbase + r;
        float v = acc[i][jj][r] + bv;
        if (CMODE == 0){
          ((float*)C)[coff + (size_t)m*ldc + n] = v;
        } else if (CMODE == 1){
          ((unsigned short*)C)[coff + (size_t)m*ldc + n] = f2bf(v);
        } else {
          v = 0.5f * v * (1.0f + erff(v * 0.70710678118654752f));   // exact GELU
          ((unsigned short*)C)[coff + (size_t)m*ldc + n] = f2bf(v);
        }
      }
    }
  }
}

// ---------------------------------------------------------------------------
// gelu_reduce2: out[i] = bf16(gelu(p0[i] + p1[i] + bias[i % 1024])).
// ---------------------------------------------------------------------------
__global__ __launch_bounds__(256)
void gelu_reduce2(const unsigned short* __restrict__ p, size_t pstride,
                  const float* __restrict__ bias, unsigned short* __restrict__ out)
{
  const size_t i = ((size_t)blockIdx.x*256 + threadIdx.x)*8;
  const int nb = (int)(i & 1023);
  u16x8 a = *(const u16x8*)(p + i);
  u16x8 b = *(const u16x8*)(p + pstride + i);
  u16x8 o;
  #pragma unroll
  for (int j = 0; j < 8; j++){
    float v = bf2f(a[j]) + bf2f(b[j]) + bias[nb + j];
    v = 0.5f * v * (1.0f + erff(v * 0.70710678118654752f));
    o[j] = f2bf(v);
  }
  *(u16x8*)(out + i) = o;
}

// ---------------------------------------------------------------------------
// Row softmax over bf16 scores [64][512][512], in-place.  One wave per row.
// ---------------------------------------------------------------------------
template<int CAUSAL>
__global__ __launch_bounds__(256)
void softmax_rows(unsigned short* __restrict__ scores)
{
  const int row  = blockIdx.x*4 + (threadIdx.x >> 6);
  const int lane = threadIdx.x & 63;
  const int q = row & 511;
  unsigned short* srow = scores + (size_t)row*512;
  u16x8 sv = {};
  if (!CAUSAL || lane*8 <= q) sv = *(const u16x8*)(srow + lane*8);
  float s[8]; float m = -1e30f;
  #pragma unroll
  for (int i = 0; i < 8; i++){
    const int col = lane*8 + i;
    float v = bf2f(sv[i]) * 0.044194173824159216f;   // 1/sqrt(512)
    if (CAUSAL && col > q) v = -1e30f;
    s[i] = v; m = fmaxf(m, v);
  }
  #pragma unroll
  for (int o = 32; o; o >>= 1) m = fmaxf(m, __shfl_xor(m, o));
  float p[8], sum = 0.f;
  #pragma unroll
  for (int i = 0; i < 8; i++){
    float e = __expf(s[i] - m);
    if (CAUSAL && (lane*8 + i) > q) e = 0.f;
    p[i] = e; sum += e;
  }
  #pragma unroll
  for (int o = 32; o; o >>= 1) sum += __shfl_xor(sum, o);
  const float inv = 1.0f / sum;
  u16x8 pv;
  #pragma unroll
  for (int i = 0; i < 8; i++) pv[i] = f2bf(p[i] * inv);
  *(u16x8*)(srow + lane*8) = pv;
}

// ---------------------------------------------------------------------------
// y = LayerNorm(x + sum_{p<ND} partial_p + bias) * g + b.
// XF32: x is f32 (else bf16).  OUTF32: write f32 (else bf16).
// ---------------------------------------------------------------------------
template<int XF32, int OUTF32, int ND>
__global__ __launch_bounds__(256)
void ln_rows(const void* __restrict__ x, const unsigned short* __restrict__ dbase,
             size_t dstride, const float* __restrict__ bias,
             const float* __restrict__ g, const float* __restrict__ bta,
             void* __restrict__ out)
{
  const int row = blockIdx.x*4 + (threadIdx.x >> 6);
  const int lane = threadIdx.x & 63;
  float v[8];
  if (XF32){
    const float* xr = (const float*)x + (size_t)row*512 + lane*8;
    #pragma unroll
    for (int i = 0; i < 8; i++) v[i] = xr[i];
  } else {
    u16x8 xv = *(const u16x8*)((const unsigned short*)x + (size_t)row*512 + lane*8);
    #pragma unroll
    for (int i = 0; i < 8; i++) v[i] = bf2f(xv[i]);
  }
  #pragma unroll
  for (int i = 0; i < 8; i++) v[i] += bias ? bias[lane*8 + i] : 0.0f;
  #pragma unroll
  for (int p = 0; p < ND; p++){
    u16x8 dv = *(const u16x8*)(dbase + p*dstride + (size_t)row*512 + lane*8);
    #pragma unroll
    for (int i = 0; i < 8; i++) v[i] += bf2f(dv[i]);
  }
  float sum = 0.f;
  #pragma unroll
  for (int i = 0; i < 8; i++) sum += v[i];
  #pragma unroll
  for (int o = 32; o; o >>= 1) sum += __shfl_xor(sum, o);
  const float mean = sum * (1.0f/512.0f);
  float s2 = 0.f;
  #pragma unroll
  for (int i = 0; i < 8; i++){ const float t = v[i] - mean; s2 += t*t; }
  #pragma unroll
  for (int o = 32; o; o >>= 1) s2 += __shfl_xor(s2, o);
  const float inv = rsqrtf(s2 * (1.0f/512.0f) + 1e-3f);
  if (OUTF32){
    float* po = (float*)out + (size_t)row*512 + lane*8;
    #pragma unroll
    for (int i = 0; i < 8; i++){
      const int c = lane*8 + i;
      po[i] = (v[i] - mean)*inv*g[c] + bta[c];
    }
  } else {
    u16x8 ov;
    #pragma unroll
    for (int i = 0; i < 8; i++){
      const int c = lane*8 + i;
      ov[i] = f2bf((v[i] - mean)*inv*g[c] + bta[c]);
    }
    *(u16x8*)((unsigned short*)out + (size_t)row*512 + lane*8) = ov;
  }
}

struct Cast2 { const float* s[2]; unsigned short* d[2]; };

__global__ __launch_bounds__(256)
void cast_bf16_k2(Cast2 a, int n)
{
  const int z = blockIdx.y;
  const int i = (blockIdx.x*256 + threadIdx.x)*4;
  if (i < n){
    const float4 v = *(const float4*)(a.s[z] + i);
    uint2 o;
    o.x = (unsigned)f2bf(v.x) | ((unsigned)f2bf(v.y) << 16);
    o.y = (unsigned)f2bf(v.z) | ((unsigned)f2bf(v.w) << 16);
    *(uint2*)(a.d[z] + i) = o;
  }
}

// ---------------------------------------------------------------------------
// transpose_cast_all: 10 weight tensors, one dispatch.
// ---------------------------------------------------------------------------
struct TCA {
  const float* s[10]; unsigned short* d[10];
  int Cc[10]; int Rr[10]; int cw[10];
  int start[11];
};

__global__ __launch_bounds__(256)
void transpose_cast_all(TCA a)
{
  __shared__ float tile[32][33];
  const int bid = blockIdx.x;
  int t = 0;
  #pragma unroll
  for (int k = 0; k < 9; k++) if (bid >= a.start[k+1]) t = k+1;
  const float* src = a.s[t];
  unsigned short* dst = a.d[t];
  const int C = a.Cc[t], R = a.Rr[t];
  const int local = bid - a.start[t];
  const int bx = (local % a.cw[t])*32, by = (local / a.cw[t])*32;
  const int tx = threadIdx.x & 31, ty = threadIdx.x >> 5;
  #pragma unroll
  for (int i = 0; i < 32; i += 8) tile[ty + i][tx] = src[(size_t)(by + ty + i)*C + bx + tx];
  __syncthreads();
  #pragma unroll
  for (int i = 0; i < 32; i += 8) dst[(size_t)(bx + ty + i)*R + by + tx] = f2bf(tile[tx][ty + i]);
}

// ---------------------------------------------------------------------------
extern "C" void kernel_launch(void* const* d_in, const int* in_sizes, int n_in,
                              void* d_out, int out_size, void* d_ws, size_t ws_size,
                              hipStream_t stream)
{
  (void)in_sizes; (void)n_in; (void)out_size; (void)ws_size;

  const float* in_seq  = (const float*)d_in[0];
  const float* out_seq = (const float*)d_in[1];
  const float* sa_wq = (const float*)d_in[2];  const float* sa_bq = (const float*)d_in[3];
  const float* sa_wk = (const float*)d_in[4];  const float* sa_bk = (const float*)d_in[5];
  const float* sa_wv = (const float*)d_in[6];  const float* sa_bv = (const float*)d_in[7];
  const float* sa_wo = (const float*)d_in[8];  const float* sa_bo = (const float*)d_in[9];
  const float* sa_lng = (const float*)d_in[10]; const float* sa_lnb = (const float*)d_in[11];
  const float* ca_wq = (const float*)d_in[12]; const float* ca_bq = (const float*)d_in[13];
  const float* ca_wk = (const float*)d_in[14]; const float* ca_bk = (const float*)d_in[15];
  const float* ca_wv = (const float*)d_in[16]; const float* ca_bv = (const float*)d_in[17];
  const float* ca_wo = (const float*)d_in[18]; const float* ca_bo = (const float*)d_in[19];
  const float* ca_lng = (const float*)d_in[20]; const float* ca_lnb = (const float*)d_in[21];
  const float* ff_w1 = (const float*)d_in[22]; const float* ff_b1 = (const float*)d_in[23];
  const float* ff_w2 = (const float*)d_in[24]; const float* ff_b2 = (const float*)d_in[25];
  const float* ff_lng = (const float*)d_in[26]; const float* ff_lnb = (const float*)d_in[27];

  char* ws = (char*)d_ws;
  size_t off = 0;
  auto alloc = [&](size_t bytes){ char* p = ws + off; off += (bytes + 255) & ~(size_t)255; return p; };

  unsigned short* wT[8];
  for (int i = 0; i < 8; i++) wT[i] = (unsigned short*)alloc(4096ULL*512*2);
  unsigned short* w1T  = (unsigned short*)alloc(1024ULL*512*2);
  unsigned short* w2T  = (unsigned short*)alloc(512ULL*1024*2);
  unsigned short* xbf  = (unsigned short*)alloc(4096ULL*512*2);   // running residual (bf16)
  unsigned short* inbf = (unsigned short*)alloc(4096ULL*512*2);
  unsigned short* qb   = (unsigned short*)alloc(4096ULL*4096*2);  // also FFN hidden
  unsigned short* kb   = (unsigned short*)alloc(4096ULL*4096*2);  // also attn-out
  unsigned short* vT   = (unsigned short*)alloc(64ULL*512*512*2);
  unsigned short* scb  = (unsigned short*)alloc(64ULL*512*512*2); // scores/probs/partials

  unsigned short* part = scb;
  const size_t PART_STRIDE = 2097152;   // ushorts per [4096][512] slice
  const size_t FF1_STRIDE = 4194304;    // ushorts per [4096][1024] slice

  // ---- prologue ----
  Cast2 c2{{out_seq, in_seq}, {xbf, inbf}};
  cast_bf16_k2<<<dim3(2048,2), 256, 0, stream>>>(c2, 4096*512);

  TCA ta;
  const float* srcs[10] = {sa_wq, sa_wk, sa_wv, ca_wq, ca_wk, ca_wv, sa_wo, ca_wo, ff_w1, ff_w2};
  unsigned short* dsts[10] = {wT[0], wT[1], wT[2], wT[4], wT[5], wT[6], wT[3], wT[7], w1T, w2T};
  const int Rs[10] = {512,512,512,512,512,512, 4096,4096, 512, 1024};
  const int Cs[10] = {4096,4096,4096,4096,4096,4096, 512,512, 1024, 512};
  int acc_ = 0;
  for (int t = 0; t < 10; t++){
    ta.s[t] = srcs[t]; ta.d[t] = dsts[t];
    ta.Rr[t] = Rs[t]; ta.Cc[t] = Cs[t]; ta.cw[t] = Cs[t]/32;
    ta.start[t] = acc_;
    acc_ += (Cs[t]/32)*(Rs[t]/32);
  }
  ta.start[10] = acc_;
  transpose_cast_all<<<acc_, 256, 0, stream>>>(ta);

  #define G256(MODE, CSK, Apt, Bpt, Cpt, BIAS, M, N, K, LDA, LDB, LDC, Z, aH, aB, bH, bB, cH, cB) \
    gemm256<MODE, CSK><<<dim3((N)/256,(M)/256,(Z)), 512, 0, stream>>>( \
      (const unsigned short*)(Apt), (const unsigned short*)(Bpt), (void*)(Cpt), BIAS, \
      M, N, K, LDA, LDB, LDC, aH, aB, bH, bB, cH, cB)

  // ---- self-attention (causal) ----
  Proj3 saP{{xbf, xbf, wT[2]}, {wT[0], wT[1], xbf}, {qb, kb, vT}, {sa_bq, sa_bk, sa_bv}};
  qkv256<<<dim3(16,16,3), 512, 0, stream>>>(saP);
  G256(1, 1, qb, kb, scb, nullptr, 512, 512, 512, 4096, 4096, 512, 64,
       512, 2097152, 512, 2097152, 262144, 2097152);
  softmax_rows<1><<<8192, 256, 0, stream>>>(scb);
  G256(1, 2, scb, vT, kb, nullptr, 512, 512, 512, 512, 512, 4096, 64,
       262144, 2097152, 262144, 2097152, 512, 2097152);
  G256(1, 0, kb, wT[3], part, nullptr, 4096, 512, 512, 4096, 4096, 512, 8,
       512, 0, 512, 0, PART_STRIDE, 0);
  ln_rows<1, 0, 8><<<1024, 256, 0, stream>>>(out_seq, part, PART_STRIDE,
                                             sa_bo, sa_lng, sa_lnb, xbf);

  // ---- cross-attention ----
  Proj3 caP{{xbf, inbf, wT[6]}, {wT[4], wT[5], inbf}, {qb, kb, vT}, {ca_bq, ca_bk, ca_bv}};
  qkv256<<<dim3(16,16,3), 512, 0, stream>>>(caP);
  G256(1, 0, qb, kb, scb, nullptr, 512, 512, 512, 4096, 4096, 512, 64,
       512, 2097152, 512, 2097152, 262144, 2097152);
  softmax_rows<0><<<8192, 256, 0, stream>>>(scb);
  G256(1, 0, scb, vT, kb, nullptr, 512, 512, 512, 512, 512, 4096, 64,
       262144, 2097152, 262144, 2097152, 512, 2097152);
  G256(1, 0, kb, wT[7], part, nullptr, 4096, 512, 512, 4096, 4096, 512, 8,
       512, 0, 512, 0, PART_STRIDE, 0);
  ln_rows<0, 0, 8><<<1024, 256, 0, stream>>>(xbf, part, PART_STRIDE,
                                             ca_bo, ca_lng, ca_lnb, xbf);

  // ---- FFN ----
  gemm_bt<1><<<dim3(8,32,2), 256, 0, stream>>>(
      xbf, w1T, (void*)part, nullptr, 4096, 1024, 256, 512, 512, 1024,
      256, 256, FF1_STRIDE);
  gelu_reduce2<<<2048, 256, 0, stream>>>(part, FF1_STRIDE, ff_b1, qb);
  G256(1, 0, qb, w2T, part, nullptr, 4096, 512, 128, 1024, 1024, 512, 8,
       128, 0, 128, 0, PART_STRIDE, 0);
  ln_rows<0, 1, 8><<<1024, 256, 0, stream>>>(xbf, part, PART_STRIDE,
                                             ff_b2, ff_lng, ff_lnb, (float*)d_out);

  #undef G256
}